// Round 2
// baseline (3257.175 us; speedup 1.0000x reference)
//
#include <hip/hip_runtime.h>
#include <hip/hip_bf16.h>

#define N_NODES 50000
#define N_PAD   50048      // padded to 64-row multiple for guard-free GEMM tiles
#define N_EDGES 800000
#define DF 128

// LDS row stride (ushorts): 128 bf16 + 8 pad (272 B = 17*16 B)
#define HS 136

typedef __bf16 bf16x8 __attribute__((ext_vector_type(8)));
typedef float f32x4 __attribute__((ext_vector_type(4)));
typedef unsigned int uint4v __attribute__((ext_vector_type(4)));
typedef unsigned short us4 __attribute__((ext_vector_type(4)));
typedef unsigned short us8 __attribute__((ext_vector_type(8)));

__device__ __forceinline__ unsigned short f2bf(float f) {
  unsigned u = __builtin_bit_cast(unsigned, f);
  u += 0x7FFFu + ((u >> 16) & 1u);   // RNE
  return (unsigned short)(u >> 16);
}
__device__ __forceinline__ float bf2f(unsigned short u) {
  return __builtin_bit_cast(float, ((unsigned)u) << 16);
}

// Pack fp32 row-major W[128][128] (optionally W - Wsub) into bf16 MFMA
// B-fragment order: out[((ct*4 + kc)*64 + l)*8 + j] =
//   bf16(W[kc*32 + (l>>4)*8 + j][ct*16 + (l&15)])
__global__ void pack_w(const float* __restrict__ W,
                       const float* __restrict__ Wsub,
                       unsigned short* __restrict__ out) {
  const int idx = blockIdx.x * blockDim.x + threadIdx.x;   // < 2048
  const int l = idx & 63;
  const int blk = idx >> 6;
  const int ct = blk >> 2;
  const int kc = blk & 3;
  const int col = ct * 16 + (l & 15);
  const int k0 = kc * 32 + (l >> 4) * 8;
  unsigned short tmp[8];
#pragma unroll
  for (int j = 0; j < 8; ++j) {
    float v = W[(size_t)(k0 + j) * DF + col];
    if (Wsub) v -= Wsub[(size_t)(k0 + j) * DF + col];
    tmp[j] = f2bf(v);
  }
  us4 lo = { tmp[0], tmp[1], tmp[2], tmp[3] };
  us4 hi = { tmp[4], tmp[5], tmp[6], tmp[7] };
  us4* o = (us4*)(out + (size_t)idx * 8);
  o[0] = lo;
  o[1] = hi;
}

__global__ void deg_kernel(const int* __restrict__ dst, int* __restrict__ deg) {
  const int e = blockIdx.x * 256 + threadIdx.x;
  if (e < N_EDGES) atomicAdd(&deg[dst[e]], 1);
}

// Node-level GEMM: out[r] = bf16( in[r] @ Wp + bias_mode )
// BIAS_MODE: 0 none, 1 bias[col], 2 deg[row]*bias[col]
template<int BIAS_MODE, bool IN_BF16>
__global__ __launch_bounds__(256)
void node_gemm(const void* __restrict__ in,
               const unsigned short* __restrict__ wp,
               const float* __restrict__ bias,
               const int* __restrict__ deg,
               unsigned short* __restrict__ out,
               int nrows_valid) {
  __shared__ unsigned short xs[64 * HS];
  const int t = threadIdx.x;
  const int r0 = blockIdx.x * 64;

  // stage 64 input rows -> LDS bf16
  {
    const int e = t >> 2, q = t & 3;
    const int grow = r0 + e;
    if (IN_BF16) {
      const us8* src = (const us8*)((const unsigned short*)in + (size_t)grow * DF + q * 32);
#pragma unroll
      for (int i = 0; i < 4; ++i) {
        us8 v = {};
        if (grow < nrows_valid) v = src[i];
        *(us8*)&xs[e * HS + q * 32 + i * 8] = v;
      }
    } else {
      const float4* src = (const float4*)((const float*)in + (size_t)grow * DF) + q * 8;
#pragma unroll
      for (int i = 0; i < 8; ++i) {
        float4 v = { 0.f, 0.f, 0.f, 0.f };
        if (grow < nrows_valid) v = src[i];
        us4 p = { f2bf(v.x), f2bf(v.y), f2bf(v.z), f2bf(v.w) };
        *(us4*)&xs[e * HS + q * 32 + i * 4] = p;
      }
    }
  }
  __syncthreads();

  const int w = t >> 6, l = t & 63, l15 = l & 15, lg = l >> 4;
  f32x4 acc[4][2] = {};
  const uint4v* wv = (const uint4v*)wp;
#pragma unroll
  for (int kc = 0; kc < 4; ++kc) {
    bf16x8 afr[4];
#pragma unroll
    for (int rt = 0; rt < 4; ++rt)
      afr[rt] = __builtin_bit_cast(bf16x8,
          *(const uint4v*)&xs[(rt * 16 + l15) * HS + kc * 32 + lg * 8]);
#pragma unroll
    for (int c = 0; c < 2; ++c) {
      bf16x8 bfr = __builtin_bit_cast(bf16x8, wv[((w * 2 + c) * 4 + kc) * 64 + l]);
#pragma unroll
      for (int rt = 0; rt < 4; ++rt)
        acc[rt][c] = __builtin_amdgcn_mfma_f32_16x16x32_bf16(afr[rt], bfr, acc[rt][c], 0, 0, 0);
    }
  }

#pragma unroll
  for (int c = 0; c < 2; ++c) {
    const int col = w * 32 + c * 16 + l15;
    const float bcol = (BIAS_MODE >= 1) ? bias[col] : 0.f;
#pragma unroll
    for (int rt = 0; rt < 4; ++rt) {
#pragma unroll
      for (int r = 0; r < 4; ++r) {
        const int grow = r0 + rt * 16 + lg * 4 + r;
        float bv = bcol;
        if (BIAS_MODE == 2) bv = (float)deg[grow] * bcol;
        out[(size_t)grow * DF + col] = f2bf(acc[rt][c][r] + bv);  // out is N_PAD-padded
      }
    }
  }
}

// Layer-1 edge pass: Hsum[dst] += relu(A[dst] + B[src]); 16 edges/block.
__global__ __launch_bounds__(256)
void edge_h_scatter(const unsigned short* __restrict__ A,
                    const unsigned short* __restrict__ B,
                    const int* __restrict__ src,
                    const int* __restrict__ dst,
                    float* __restrict__ Hsum) {
  const int t = threadIdx.x;
  const int ge = blockIdx.x * 16 + (t >> 4);
  const int lane16 = t & 15;
  const int si = src[ge];
  const int di = dst[ge];
  us8 av = *(const us8*)(A + (size_t)di * DF + lane16 * 8);
  us8 bv = *(const us8*)(B + (size_t)si * DF + lane16 * 8);
  float* hp = Hsum + (size_t)di * DF + lane16 * 8;
#pragma unroll
  for (int j = 0; j < 8; ++j) {
    float v = bf2f(av[j]) + bf2f(bv[j]);
    v = v > 0.f ? v : 0.f;
    unsafeAtomicAdd(hp + j, v);
  }
}

// Layer-2 edge pass: h = relu(A2[dst]+B2[src]); msg = h@W2 + b2;
// write msg, atomically scatter into feat_out. 64 edges/block, 4 waves.
__global__ __launch_bounds__(256)
void edge_msg(const unsigned short* __restrict__ A,
              const unsigned short* __restrict__ B,
              const int* __restrict__ src,
              const int* __restrict__ dst,
              const unsigned short* __restrict__ w2p,
              const float* __restrict__ b2,
              float* __restrict__ feat_out,
              float* __restrict__ msg_out) {
  __shared__ unsigned short h_s[64 * HS];
  __shared__ int dst_s[64];
  const int t = threadIdx.x;
  const int e0 = blockIdx.x * 64;

  {
    const int e = t >> 2, q = t & 3;
    const int ge = e0 + e;
    const int si = src[ge];
    const int di = dst[ge];
    if (q == 0) dst_s[e] = di;
    const us8* ap = (const us8*)(A + (size_t)di * DF + q * 32);
    const us8* bp = (const us8*)(B + (size_t)si * DF + q * 32);
#pragma unroll
    for (int i = 0; i < 4; ++i) {
      us8 av = ap[i];
      us8 bv = bp[i];
      us8 h;
#pragma unroll
      for (int j = 0; j < 8; ++j) {
        float v = bf2f(av[j]) + bf2f(bv[j]);
        v = v > 0.f ? v : 0.f;
        h[j] = f2bf(v);
      }
      *(us8*)&h_s[e * HS + q * 32 + i * 8] = h;
    }
  }
  __syncthreads();

  const int w = t >> 6, l = t & 63, l15 = l & 15, lg = l >> 4;
  f32x4 acc[4][2] = {};
  const uint4v* wv = (const uint4v*)w2p;
#pragma unroll
  for (int kc = 0; kc < 4; ++kc) {
    bf16x8 afr[4];
#pragma unroll
    for (int rt = 0; rt < 4; ++rt)
      afr[rt] = __builtin_bit_cast(bf16x8,
          *(const uint4v*)&h_s[(rt * 16 + l15) * HS + kc * 32 + lg * 8]);
#pragma unroll
    for (int c = 0; c < 2; ++c) {
      bf16x8 bfr = __builtin_bit_cast(bf16x8, wv[((w * 2 + c) * 4 + kc) * 64 + l]);
#pragma unroll
      for (int rt = 0; rt < 4; ++rt)
        acc[rt][c] = __builtin_amdgcn_mfma_f32_16x16x32_bf16(afr[rt], bfr, acc[rt][c], 0, 0, 0);
    }
  }

#pragma unroll
  for (int c = 0; c < 2; ++c) {
    const int col = w * 32 + c * 16 + l15;
    const float bv = b2[col];
#pragma unroll
    for (int rt = 0; rt < 4; ++rt) {
#pragma unroll
      for (int r = 0; r < 4; ++r) {
        const int row = rt * 16 + lg * 4 + r;
        const float v = acc[rt][c][r] + bv;
        msg_out[(size_t)(e0 + row) * DF + col] = v;
        unsafeAtomicAdd(&feat_out[(size_t)dst_s[row] * DF + col], v);
      }
    }
  }
}

extern "C" void kernel_launch(void* const* d_in, const int* in_sizes, int n_in,
                              void* d_out, int out_size, void* d_ws, size_t ws_size,
                              hipStream_t stream) {
  const float* x    = (const float*)d_in[0];
  const int*   eidx = (const int*)d_in[1];
  const float* W1_0 = (const float*)d_in[2];
  const float* b1_0 = (const float*)d_in[3];
  const float* W2_0 = (const float*)d_in[4];
  const float* b2_0 = (const float*)d_in[5];
  const float* W1_1 = (const float*)d_in[6];
  const float* b1_1 = (const float*)d_in[7];
  const float* W2_1 = (const float*)d_in[8];
  const float* b2_1 = (const float*)d_in[9];

  const int* src = eidx;
  const int* dst = eidx + N_EDGES;

  float* feat2 = (float*)d_out;
  float* msg2  = feat2 + (size_t)N_NODES * DF;

  // ---- workspace layout (all N_PAD-padded) ----
  char* ws = (char*)d_ws;
  const size_t BF_ROWS = (size_t)N_PAD * DF;            // elements
  unsigned short* A     = (unsigned short*)ws;          ws += BF_ROWS * 2;   // 12.8 MB
  unsigned short* Bm    = (unsigned short*)ws;          ws += BF_ROWS * 2;   // 12.8 MB
  unsigned short* feat1 = (unsigned short*)ws;          ws += BF_ROWS * 2;   // 12.8 MB
  float*          Hsum  = (float*)ws;                   ws += BF_ROWS * 4;   // 25.6 MB
  int*            deg   = (int*)ws;                     ws += (size_t)N_PAD * 4;
  unsigned short* wa1p  = (unsigned short*)ws;          ws += 16384 * 2;
  unsigned short* wb1p  = (unsigned short*)ws;          ws += 16384 * 2;
  unsigned short* w20p  = (unsigned short*)ws;          ws += 16384 * 2;
  unsigned short* wa2p  = (unsigned short*)ws;          ws += 16384 * 2;
  unsigned short* wb2p  = (unsigned short*)ws;          ws += 16384 * 2;
  unsigned short* w21p  = (unsigned short*)ws;          ws += 16384 * 2;

  hipMemsetAsync(Hsum, 0, BF_ROWS * 4, stream);
  hipMemsetAsync(deg, 0, (size_t)N_PAD * 4, stream);
  hipMemsetAsync(feat2, 0, (size_t)N_NODES * DF * 4, stream);

  // W1 is [256][128]: rows 0..127 multiply x_i, rows 128..255 multiply (x_j - x_i).
  // Wa = top - bot (applies to x_i), Wb = bot (applies to x_j).
  pack_w<<<8, 256, 0, stream>>>(W1_0, W1_0 + 128 * DF, wa1p);
  pack_w<<<8, 256, 0, stream>>>(W1_0 + 128 * DF, nullptr, wb1p);
  pack_w<<<8, 256, 0, stream>>>(W2_0, nullptr, w20p);
  pack_w<<<8, 256, 0, stream>>>(W1_1, W1_1 + 128 * DF, wa2p);
  pack_w<<<8, 256, 0, stream>>>(W1_1 + 128 * DF, nullptr, wb2p);
  pack_w<<<8, 256, 0, stream>>>(W2_1, nullptr, w21p);

  deg_kernel<<<(N_EDGES + 255) / 256, 256, 0, stream>>>(dst, deg);

  const int NG = N_PAD / 64;  // 782 node-GEMM blocks

  // Layer 1: A1 = x@Wa + b1, B1 = x@Wb
  node_gemm<1, false><<<NG, 256, 0, stream>>>(x, wa1p, b1_0, nullptr, A, N_NODES);
  node_gemm<0, false><<<NG, 256, 0, stream>>>(x, wb1p, nullptr, nullptr, Bm, N_NODES);
  // Hsum[dst] += relu(A[dst] + B[src])
  edge_h_scatter<<<N_EDGES / 16, 256, 0, stream>>>(A, Bm, src, dst, Hsum);
  // feat1 = Hsum@W2_0 + deg*b2_0   (bf16)
  node_gemm<2, false><<<NG, 256, 0, stream>>>(Hsum, w20p, b2_0, deg, feat1, N_PAD);

  // Layer 2: A2 = feat1@Wa2 + b1_1, B2 = feat1@Wb2
  node_gemm<1, true><<<NG, 256, 0, stream>>>(feat1, wa2p, b1_1, nullptr, A, N_PAD);
  node_gemm<0, true><<<NG, 256, 0, stream>>>(feat1, wb2p, nullptr, nullptr, Bm, N_PAD);
  // msg2 = relu(A2[dst]+B2[src])@W2_1 + b2_1 ; feat2 = scatter-add(msg2)
  edge_msg<<<N_EDGES / 64, 256, 0, stream>>>(A, Bm, src, dst, w21p, b2_1, feat2, msg2);
}

// Round 3
// 521.473 us; speedup vs baseline: 6.2461x; 6.2461x over previous
//
#include <hip/hip_runtime.h>
#include <hip/hip_bf16.h>

#define N_NODES 50000
#define N_PAD   50048      // padded to 64-row multiple for guard-free GEMM tiles
#define N_EDGES 800000
#define DF 128

// LDS row stride (ushorts): 128 bf16 + 8 pad (272 B = 17*16 B)
#define HS 136

typedef __bf16 bf16x8 __attribute__((ext_vector_type(8)));
typedef float f32x4 __attribute__((ext_vector_type(4)));
typedef unsigned int uint4v __attribute__((ext_vector_type(4)));
typedef unsigned short us4 __attribute__((ext_vector_type(4)));
typedef unsigned short us8 __attribute__((ext_vector_type(8)));

__device__ __forceinline__ unsigned short f2bf(float f) {
  unsigned u = __builtin_bit_cast(unsigned, f);
  u += 0x7FFFu + ((u >> 16) & 1u);   // RNE
  return (unsigned short)(u >> 16);
}
__device__ __forceinline__ float bf2f(unsigned short u) {
  return __builtin_bit_cast(float, ((unsigned)u) << 16);
}

// Pack fp32 row-major W[128][128] (optionally W - Wsub) into bf16 MFMA
// B-fragment order.
__global__ void pack_w(const float* __restrict__ W,
                       const float* __restrict__ Wsub,
                       unsigned short* __restrict__ out) {
  const int idx = blockIdx.x * blockDim.x + threadIdx.x;   // < 2048
  const int l = idx & 63;
  const int blk = idx >> 6;
  const int ct = blk >> 2;
  const int kc = blk & 3;
  const int col = ct * 16 + (l & 15);
  const int k0 = kc * 32 + (l >> 4) * 8;
  unsigned short tmp[8];
#pragma unroll
  for (int j = 0; j < 8; ++j) {
    float v = W[(size_t)(k0 + j) * DF + col];
    if (Wsub) v -= Wsub[(size_t)(k0 + j) * DF + col];
    tmp[j] = f2bf(v);
  }
  us4 lo = { tmp[0], tmp[1], tmp[2], tmp[3] };
  us4 hi = { tmp[4], tmp[5], tmp[6], tmp[7] };
  us4* o = (us4*)(out + (size_t)idx * 8);
  o[0] = lo;
  o[1] = hi;
}

__global__ void deg_kernel(const int* __restrict__ dst, int* __restrict__ deg) {
  const int e = blockIdx.x * 256 + threadIdx.x;
  if (e < N_EDGES) atomicAdd(&deg[dst[e]], 1);
}

// Single-block exclusive scan of deg[N_PAD] -> row_ptr[N_PAD+1], cursor copy.
#define SCAN_T 1024
#define SCAN_CHUNK ((N_PAD + SCAN_T - 1) / SCAN_T)
__global__ __launch_bounds__(SCAN_T)
void scan_kernel(const int* __restrict__ deg,
                 int* __restrict__ row_ptr,
                 int* __restrict__ cursor) {
  __shared__ int part[SCAN_T];
  const int t = threadIdx.x;
  const int lo = t * SCAN_CHUNK;
  const int hi = min(lo + SCAN_CHUNK, N_PAD);
  int s = 0;
  for (int i = lo; i < hi; ++i) s += deg[i];
  part[t] = s;
  __syncthreads();
  for (int off = 1; off < SCAN_T; off <<= 1) {
    int v = (t >= off) ? part[t - off] : 0;
    __syncthreads();
    part[t] += v;
    __syncthreads();
  }
  int run = (t > 0) ? part[t - 1] : 0;
  for (int i = lo; i < hi; ++i) {
    row_ptr[i] = run;
    cursor[i] = run;
    run += deg[i];
  }
  if (t == SCAN_T - 1) row_ptr[N_PAD] = part[SCAN_T - 1];
}

// Scatter src ids into dst-sorted order.
__global__ void sort_kernel(const int* __restrict__ src,
                            const int* __restrict__ dst,
                            int* __restrict__ cursor,
                            int* __restrict__ sorted_src) {
  const int e = blockIdx.x * 256 + threadIdx.x;
  const int d = dst[e];
  const int pos = atomicAdd(&cursor[d], 1);
  sorted_src[pos] = src[e];
}

// Per-node aggregation: Hsum[n] = sum_{e in CSR(n)} relu(A[n] + B[src[e]]).
// 16 lanes per node (8 cols each), fp32 accumulate, bf16 write.
__global__ __launch_bounds__(256)
void aggregate(const unsigned short* __restrict__ A,
               const unsigned short* __restrict__ B,
               const int* __restrict__ row_ptr,
               const int* __restrict__ sorted_src,
               unsigned short* __restrict__ Hsum) {
  const int t = threadIdx.x;
  const int n = blockIdx.x * 16 + (t >> 4);
  const int lane = t & 15;
  const int beg = row_ptr[n];
  const int end = row_ptr[n + 1];
  us8 av = *(const us8*)(A + (size_t)n * DF + lane * 8);
  float af[8];
#pragma unroll
  for (int j = 0; j < 8; ++j) af[j] = bf2f(av[j]);
  float acc[8] = {};
  for (int k = beg; k < end; ++k) {
    const int s = sorted_src[k];
    us8 bv = *(const us8*)(B + (size_t)s * DF + lane * 8);
#pragma unroll
    for (int j = 0; j < 8; ++j) {
      float v = af[j] + bf2f(bv[j]);
      acc[j] += v > 0.f ? v : 0.f;
    }
  }
  us8 o;
#pragma unroll
  for (int j = 0; j < 8; ++j) o[j] = f2bf(acc[j]);
  *(us8*)(Hsum + (size_t)n * DF + lane * 8) = o;
}

// Node-level GEMM: out[r] = in[r] @ Wp + bias_mode
// BIAS_MODE: 0 none, 1 bias[col], 2 deg[row]*bias[col]
template<int BIAS_MODE, bool IN_BF16, bool OUT_F32>
__global__ __launch_bounds__(256)
void node_gemm(const void* __restrict__ in,
               const unsigned short* __restrict__ wp,
               const float* __restrict__ bias,
               const int* __restrict__ deg,
               void* __restrict__ outv,
               int nrows_in, int nrows_out) {
  __shared__ unsigned short xs[64 * HS];
  const int t = threadIdx.x;
  const int r0 = blockIdx.x * 64;

  {
    const int e = t >> 2, q = t & 3;
    const int grow = r0 + e;
    if (IN_BF16) {
      const us8* src = (const us8*)((const unsigned short*)in + (size_t)grow * DF + q * 32);
#pragma unroll
      for (int i = 0; i < 4; ++i) {
        us8 v = {};
        if (grow < nrows_in) v = src[i];
        *(us8*)&xs[e * HS + q * 32 + i * 8] = v;
      }
    } else {
      const float4* src = (const float4*)((const float*)in + (size_t)grow * DF) + q * 8;
#pragma unroll
      for (int i = 0; i < 8; ++i) {
        float4 v = { 0.f, 0.f, 0.f, 0.f };
        if (grow < nrows_in) v = src[i];
        us4 p = { f2bf(v.x), f2bf(v.y), f2bf(v.z), f2bf(v.w) };
        *(us4*)&xs[e * HS + q * 32 + i * 4] = p;
      }
    }
  }
  __syncthreads();

  const int w = t >> 6, l = t & 63, l15 = l & 15, lg = l >> 4;
  f32x4 acc[4][2] = {};
  const uint4v* wv = (const uint4v*)wp;
#pragma unroll
  for (int kc = 0; kc < 4; ++kc) {
    bf16x8 afr[4];
#pragma unroll
    for (int rt = 0; rt < 4; ++rt)
      afr[rt] = __builtin_bit_cast(bf16x8,
          *(const uint4v*)&xs[(rt * 16 + l15) * HS + kc * 32 + lg * 8]);
#pragma unroll
    for (int c = 0; c < 2; ++c) {
      bf16x8 bfr = __builtin_bit_cast(bf16x8, wv[((w * 2 + c) * 4 + kc) * 64 + l]);
#pragma unroll
      for (int rt = 0; rt < 4; ++rt)
        acc[rt][c] = __builtin_amdgcn_mfma_f32_16x16x32_bf16(afr[rt], bfr, acc[rt][c], 0, 0, 0);
    }
  }

#pragma unroll
  for (int c = 0; c < 2; ++c) {
    const int col = w * 32 + c * 16 + l15;
    const float bcol = (BIAS_MODE >= 1) ? bias[col] : 0.f;
#pragma unroll
    for (int rt = 0; rt < 4; ++rt) {
#pragma unroll
      for (int r = 0; r < 4; ++r) {
        const int grow = r0 + rt * 16 + lg * 4 + r;
        if (grow >= nrows_out) continue;
        float bv = bcol;
        if (BIAS_MODE == 2) bv = (float)deg[grow] * bcol;
        const float v = acc[rt][c][r] + bv;
        if (OUT_F32) ((float*)outv)[(size_t)grow * DF + col] = v;
        else ((unsigned short*)outv)[(size_t)grow * DF + col] = f2bf(v);
      }
    }
  }
}

// Layer-2 per-edge GEMM: msg = relu(A2[dst]+B2[src]) @ W2 + b2, written in
// ORIGINAL edge order. No atomics.
__global__ __launch_bounds__(256)
void edge_msg(const unsigned short* __restrict__ A,
              const unsigned short* __restrict__ B,
              const int* __restrict__ src,
              const int* __restrict__ dst,
              const unsigned short* __restrict__ w2p,
              const float* __restrict__ b2,
              float* __restrict__ msg_out) {
  __shared__ unsigned short h_s[64 * HS];
  const int t = threadIdx.x;
  const int e0 = blockIdx.x * 64;

  {
    const int e = t >> 2, q = t & 3;
    const int ge = e0 + e;
    const int si = src[ge];
    const int di = dst[ge];
    const us8* ap = (const us8*)(A + (size_t)di * DF + q * 32);
    const us8* bp = (const us8*)(B + (size_t)si * DF + q * 32);
#pragma unroll
    for (int i = 0; i < 4; ++i) {
      us8 av = ap[i];
      us8 bv = bp[i];
      us8 h;
#pragma unroll
      for (int j = 0; j < 8; ++j) {
        float v = bf2f(av[j]) + bf2f(bv[j]);
        v = v > 0.f ? v : 0.f;
        h[j] = f2bf(v);
      }
      *(us8*)&h_s[e * HS + q * 32 + i * 8] = h;
    }
  }
  __syncthreads();

  const int w = t >> 6, l = t & 63, l15 = l & 15, lg = l >> 4;
  f32x4 acc[4][2] = {};
  const uint4v* wv = (const uint4v*)w2p;
#pragma unroll
  for (int kc = 0; kc < 4; ++kc) {
    bf16x8 afr[4];
#pragma unroll
    for (int rt = 0; rt < 4; ++rt)
      afr[rt] = __builtin_bit_cast(bf16x8,
          *(const uint4v*)&h_s[(rt * 16 + l15) * HS + kc * 32 + lg * 8]);
#pragma unroll
    for (int c = 0; c < 2; ++c) {
      bf16x8 bfr = __builtin_bit_cast(bf16x8, wv[((w * 2 + c) * 4 + kc) * 64 + l]);
#pragma unroll
      for (int rt = 0; rt < 4; ++rt)
        acc[rt][c] = __builtin_amdgcn_mfma_f32_16x16x32_bf16(afr[rt], bfr, acc[rt][c], 0, 0, 0);
    }
  }

#pragma unroll
  for (int c = 0; c < 2; ++c) {
    const int col = w * 32 + c * 16 + l15;
    const float bv = b2[col];
#pragma unroll
    for (int rt = 0; rt < 4; ++rt) {
#pragma unroll
      for (int r = 0; r < 4; ++r) {
        const int row = rt * 16 + lg * 4 + r;
        msg_out[(size_t)(e0 + row) * DF + col] = acc[rt][c][r] + bv;
      }
    }
  }
}

extern "C" void kernel_launch(void* const* d_in, const int* in_sizes, int n_in,
                              void* d_out, int out_size, void* d_ws, size_t ws_size,
                              hipStream_t stream) {
  const float* x    = (const float*)d_in[0];
  const int*   eidx = (const int*)d_in[1];
  const float* W1_0 = (const float*)d_in[2];
  const float* b1_0 = (const float*)d_in[3];
  const float* W2_0 = (const float*)d_in[4];
  const float* b2_0 = (const float*)d_in[5];
  const float* W1_1 = (const float*)d_in[6];
  const float* b1_1 = (const float*)d_in[7];
  const float* W2_1 = (const float*)d_in[8];
  const float* b2_1 = (const float*)d_in[9];

  const int* src = eidx;
  const int* dst = eidx + N_EDGES;

  float* feat2 = (float*)d_out;
  float* msg2  = feat2 + (size_t)N_NODES * DF;

  // ---- workspace layout ----
  char* ws = (char*)d_ws;
  const size_t BF_ROWS = (size_t)N_PAD * DF;
  unsigned short* A     = (unsigned short*)ws;  ws += BF_ROWS * 2;      // 12.8 MB
  unsigned short* Bm    = (unsigned short*)ws;  ws += BF_ROWS * 2;      // 12.8 MB
  unsigned short* feat1 = (unsigned short*)ws;  ws += BF_ROWS * 2;      // 12.8 MB
  unsigned short* Hsum  = (unsigned short*)ws;  ws += BF_ROWS * 2;      // 12.8 MB
  int* deg        = (int*)ws;  ws += (size_t)N_PAD * 4;
  int* row_ptr    = (int*)ws;  ws += (size_t)(N_PAD + 1) * 4;
  int* cursor     = (int*)ws;  ws += (size_t)N_PAD * 4;
  int* sorted_src = (int*)ws;  ws += (size_t)N_EDGES * 4;               // 3.2 MB
  unsigned short* wa1p = (unsigned short*)ws;  ws += 16384 * 2;
  unsigned short* wb1p = (unsigned short*)ws;  ws += 16384 * 2;
  unsigned short* w20p = (unsigned short*)ws;  ws += 16384 * 2;
  unsigned short* wa2p = (unsigned short*)ws;  ws += 16384 * 2;
  unsigned short* wb2p = (unsigned short*)ws;  ws += 16384 * 2;
  unsigned short* w21p = (unsigned short*)ws;  ws += 16384 * 2;

  hipMemsetAsync(deg, 0, (size_t)N_PAD * 4, stream);

  // W1 rows 0..127 multiply x_i, rows 128..255 multiply (x_j - x_i):
  // Wa = top - bot (applies to x_i = x[dst]), Wb = bot (applies to x_j = x[src]).
  pack_w<<<8, 256, 0, stream>>>(W1_0, W1_0 + 128 * DF, wa1p);
  pack_w<<<8, 256, 0, stream>>>(W1_0 + 128 * DF, nullptr, wb1p);
  pack_w<<<8, 256, 0, stream>>>(W2_0, nullptr, w20p);
  pack_w<<<8, 256, 0, stream>>>(W1_1, W1_1 + 128 * DF, wa2p);
  pack_w<<<8, 256, 0, stream>>>(W1_1 + 128 * DF, nullptr, wb2p);
  pack_w<<<8, 256, 0, stream>>>(W2_1, nullptr, w21p);

  // CSR build
  deg_kernel<<<N_EDGES / 256, 256, 0, stream>>>(dst, deg);
  scan_kernel<<<1, SCAN_T, 0, stream>>>(deg, row_ptr, cursor);
  sort_kernel<<<N_EDGES / 256, 256, 0, stream>>>(src, dst, cursor, sorted_src);

  const int NG = N_PAD / 64;   // 782
  const int NA = N_PAD / 16;   // 3128

  // Layer 1
  node_gemm<1, false, false><<<NG, 256, 0, stream>>>(x, wa1p, b1_0, nullptr, A, N_NODES, N_PAD);
  node_gemm<0, false, false><<<NG, 256, 0, stream>>>(x, wb1p, nullptr, nullptr, Bm, N_NODES, N_PAD);
  aggregate<<<NA, 256, 0, stream>>>(A, Bm, row_ptr, sorted_src, Hsum);
  node_gemm<2, true, false><<<NG, 256, 0, stream>>>(Hsum, w20p, b2_0, deg, feat1, N_PAD, N_PAD);

  // Layer 2
  node_gemm<1, true, false><<<NG, 256, 0, stream>>>(feat1, wa2p, b1_1, nullptr, A, N_PAD, N_PAD);
  node_gemm<0, true, false><<<NG, 256, 0, stream>>>(feat1, wb2p, nullptr, nullptr, Bm, N_PAD, N_PAD);
  aggregate<<<NA, 256, 0, stream>>>(A, Bm, row_ptr, sorted_src, Hsum);
  node_gemm<2, true, true><<<NG, 256, 0, stream>>>(Hsum, w21p, b2_1, deg, feat2, N_PAD, N_NODES);

  // msg2 in original edge order (no atomics), independent of feat2
  edge_msg<<<N_EDGES / 64, 256, 0, stream>>>(A, Bm, src, dst, w21p, b2_1, msg2);
}